// Round 7
// baseline (267.817 us; speedup 1.0000x reference)
//
#include <hip/hip_runtime.h>
#include <hip/hip_bf16.h>
#include <stdint.h>

typedef unsigned short ushort_t;
typedef __attribute__((ext_vector_type(4))) float f32x4;
typedef __attribute__((ext_vector_type(8))) __bf16 bf16x8;
typedef __attribute__((ext_vector_type(8))) unsigned short ushort8;
typedef __attribute__((ext_vector_type(4))) unsigned short ushort4v;

__device__ __forceinline__ float bf2f(ushort_t u) {
  union { unsigned u32; float f; } x; x.u32 = ((unsigned)u) << 16; return x.f;
}
__device__ __forceinline__ ushort_t f2bf(float f) {
  union { float f; unsigned u; } x; x.f = f;
  unsigned r = x.u + 0x7FFF + ((x.u >> 16) & 1);
  return (ushort_t)(r >> 16);
}

// async global->LDS, 16 bytes per lane (global_load_lds_dwordx4)
__device__ __forceinline__ void gld16(const ushort_t* g, ushort_t* l) {
  __builtin_amdgcn_global_load_lds(
      (const __attribute__((address_space(1))) uint32_t*)g,
      (__attribute__((address_space(3))) uint32_t*)l, 16, 0, 0);
}

// O-GEMM split-K map: 40 (m,ks) chunks of <=512 k-elems (8 BK-iters) each.
__constant__ unsigned char OM[40] = {0, 1, 2, 3, 4, 4, 5, 5, 6,  6,  7,  7,  8,  8,
                                     8, 9, 9, 9, 10, 10, 10, 11, 11, 11, 12, 12, 12, 12,
                                     13, 13, 13, 13, 14, 14, 14, 14, 15, 15, 15, 15};
__constant__ unsigned char OKS[40] = {0, 0, 0, 0, 0, 1, 0, 1, 0, 1, 0, 1, 0, 1,
                                      2, 0, 1, 2, 0, 1, 2, 0, 1, 2, 0, 1, 2, 3,
                                      0, 1, 2, 3, 0, 1, 2, 3, 0, 1, 2, 3};

// --- merged cast fp32->bf16 (x,Wq,Wk,Wv) + rowsum zero + out zero-init ----
__global__ __launch_bounds__(256) void cast_all_kernel(
    const float* __restrict__ x, const float* __restrict__ wq,
    const float* __restrict__ wk, const float* __restrict__ wv,
    ushort_t* __restrict__ xb, ushort_t* __restrict__ wqb,
    ushort_t* __restrict__ wkb, ushort_t* __restrict__ wvb,
    float* __restrict__ rowsum, float* __restrict__ outz) {
  int blk = blockIdx.x;
  if (blk >= 4096 + 1536 + 4) {  // out zero-init: 4096 blocks x 2048 floats
    int idx = (blk - (4096 + 1536 + 4)) * 256 + threadIdx.x;
    f32x4 z = {0.f, 0.f, 0.f, 0.f};
    ((f32x4*)outz)[idx * 2] = z;
    ((f32x4*)outz)[idx * 2 + 1] = z;
    return;
  }
  if (blk >= 4096 + 1536) {  // rowsum zero: 4 blocks x 2048 floats
    int idx = (blk - (4096 + 1536)) * 256 + threadIdx.x;  // 0..1023
    f32x4 z = {0.f, 0.f, 0.f, 0.f};
    ((f32x4*)rowsum)[idx * 2] = z;
    ((f32x4*)rowsum)[idx * 2 + 1] = z;
    return;
  }
  const float* in;
  ushort_t* out;
  int i;
  if (blk < 4096) {               // x: 8388608 elems = 4096 blocks
    in = x; out = xb; i = blk * 256 + threadIdx.x;
  } else {
    int w = (blk - 4096) >> 9;    // 512 blocks per weight matrix
    int lb = (blk - 4096) & 511;
    in = (w == 0) ? wq : (w == 1) ? wk : wv;
    out = (w == 0) ? wqb : (w == 1) ? wkb : wvb;
    i = lb * 256 + threadIdx.x;
  }
  const f32x4* p = (const f32x4*)in;
  f32x4 a = p[2 * i];
  f32x4 b = p[2 * i + 1];
  ushort8 o;
  o[0] = f2bf(a[0]); o[1] = f2bf(a[1]); o[2] = f2bf(a[2]); o[3] = f2bf(a[3]);
  o[4] = f2bf(b[0]); o[5] = f2bf(b[1]); o[6] = f2bf(b[2]); o[7] = f2bf(b[3]);
  *((ushort8*)out + i) = o;
}

// ---------------- GEMM tile core: C = A * B^T ----------------
// BK=64: 32 MFMA per barrier pair. XOR k-chunk swizzle on the GLOBAL source
// offset (gld16 dest is wave-uniform+lane*16); readers un-swizzle with
// ln15&7 -> 2-way LDS aliasing only (bank conflicts measured 0).
#define BM 128
#define BN 128
#define BK 64

__device__ __forceinline__ void gemm_core(
    const ushort_t* __restrict__ A, const ushort_t* __restrict__ B, int Kd,
    int kStart, int kStop, int m0, int n0, ushort_t* As, ushort_t* Bs,
    f32x4 (&acc)[4][4]) {
  int tid = threadIdx.x;
  int lane = tid & 63;
  int wave = tid >> 6;
  int wr = (wave >> 1) * 64;
  int wc = (wave & 1) * 64;
  int ln15 = lane & 15;
  int kq = lane >> 4;

  int row = tid >> 3;                              // 0..31 (base row of chunk)
  int ksw = ((tid & 7) ^ (row & 7)) * 8;           // swizzled k-offset (elems)
  const ushort_t* aB = A + (size_t)(m0 + row) * Kd + ksw;
  const ushort_t* bB = B + (size_t)(n0 + row) * Kd + ksw;
  int xk = ln15 & 7;                               // reader un-swizzle key

  for (int k0 = kStart; k0 < kStop; k0 += BK) {
    __syncthreads();
#pragma unroll
    for (int r = 0; r < 4; ++r) {
      gld16(aB + (size_t)(32 * r) * Kd + k0, &As[(tid + 256 * r) * 8]);
      gld16(bB + (size_t)(32 * r) * Kd + k0, &Bs[(tid + 256 * r) * 8]);
    }
    __syncthreads();
#pragma unroll
    for (int s = 0; s < 2; ++s) {
      bf16x8 af[4], bfr[4];
#pragma unroll
      for (int i = 0; i < 4; ++i)
        af[i] = *(const bf16x8*)
            &As[(wr + i * 16 + ln15) * BK + (((s * 4 + kq) ^ xk) * 8)];
#pragma unroll
      for (int j = 0; j < 4; ++j)
        bfr[j] = *(const bf16x8*)
            &Bs[(wc + j * 16 + ln15) * BK + (((s * 4 + kq) ^ xk) * 8)];
#pragma unroll
      for (int i = 0; i < 4; ++i)
#pragma unroll
        for (int j = 0; j < 4; ++j)
          acc[i][j] = __builtin_amdgcn_mfma_f32_16x16x32_bf16(
              af[i], bfr[j], acc[i][j], 0, 0, 0);
    }
  }
}

// S-GEMM fused with softmax numerator. scores*scale have |s|<~2.5 so exp
// without row-max is safe; writes bf16 E=exp(s) (diag-masked) + fp32 rowsum
// atomics. __launch_bounds__ 2nd arg=3: caps unified VGPR+AGPR ~170, no acc
// spill (R3's (256,4)+overflow caused a 1.5GB-scratch disaster).
__global__ __launch_bounds__(256, 3) void gemm_sexp(
    const ushort_t* __restrict__ Qb, const ushort_t* __restrict__ Kb,
    ushort_t* __restrict__ Eb, float* __restrict__ rowsum, float scale) {
  int m0 = blockIdx.x * BM, n0 = blockIdx.y * BN;
  if (n0 > m0 + (BM - 1)) return;  // fully-masked upper tile
  int bz = blockIdx.z;
  const ushort_t* A = Qb + (size_t)bz * (2048 * 1024);
  const ushort_t* B = Kb + (size_t)bz * (2048 * 1024);

  __shared__ ushort_t As[BM * BK];
  __shared__ ushort_t Bs[BN * BK];

  f32x4 acc[4][4];
#pragma unroll
  for (int i = 0; i < 4; ++i)
#pragma unroll
    for (int j = 0; j < 4; ++j) acc[i][j] = f32x4{0.f, 0.f, 0.f, 0.f};

  gemm_core(A, B, 1024, 0, 1024, m0, n0, As, Bs, acc);

  int tid = threadIdx.x;
  int lane = tid & 63;
  int wave = tid >> 6;
  int wr = (wave >> 1) * 64;
  int wc = (wave & 1) * 64;
  int ln15 = lane & 15;
  int kq = lane >> 4;

  // C/D layout (verified m89): col = lane&15, row = (lane>>4)*4 + reg
  ushort_t* C = Eb + (size_t)bz * (2048 * 2048);
  float* rs = rowsum + (size_t)bz * 2048;
#pragma unroll
  for (int i = 0; i < 4; ++i) {
    int row0 = m0 + wr + i * 16 + kq * 4;
#pragma unroll
    for (int r = 0; r < 4; ++r) {
      int grow = row0 + r;
      float psum = 0.f;
#pragma unroll
      for (int j = 0; j < 4; ++j) {
        int col = n0 + wc + j * 16 + ln15;
        float e = (col <= grow) ? __expf(acc[i][j][r] * scale) : 0.f;
        C[(size_t)grow * 2048 + col] = f2bf(e);
        psum += e;
      }
      psum += __shfl_xor(psum, 1);
      psum += __shfl_xor(psum, 2);
      psum += __shfl_xor(psum, 4);
      psum += __shfl_xor(psum, 8);
      if (ln15 == 0) atomicAdd(&rs[grow], psum);
    }
  }
}

// O-GEMM split-K: block = (m,ks) chunk from constant map (all ~8 BK-iters ->
// balanced regardless of CU assignment; unsplit causal blocks ranged 2..32
// iters and a CU could host two 32-iter blocks -> ~55us tail). Each block
// scales its partial by 1/rowsum (linear) and atomicAdds fp32 into out
// (zero-initialized in cast_all).
__global__ __launch_bounds__(256, 3) void gemm_osplit(
    const ushort_t* __restrict__ Eb, const ushort_t* __restrict__ Vt,
    float* __restrict__ Og, const float* __restrict__ rowsum) {
  int m = OM[blockIdx.x], ks = OKS[blockIdx.x];
  int m0 = m * BM, n0 = blockIdx.y * BN;
  int bz = blockIdx.z;
  int kEnd = m0 + BM;
  int kStart = ks * 512;
  int kStop = min(kEnd, kStart + 512);

  const ushort_t* A = Eb + (size_t)bz * (2048 * 2048);
  const ushort_t* B = Vt + (size_t)bz * (1024 * 2048);

  __shared__ ushort_t As[BM * BK];
  __shared__ ushort_t Bs[BN * BK];

  f32x4 acc[4][4];
#pragma unroll
  for (int i = 0; i < 4; ++i)
#pragma unroll
    for (int j = 0; j < 4; ++j) acc[i][j] = f32x4{0.f, 0.f, 0.f, 0.f};

  gemm_core(A, B, 2048, kStart, kStop, m0, n0, As, Bs, acc);

  int tid = threadIdx.x;
  int lane = tid & 63;
  int wave = tid >> 6;
  int wr = (wave >> 1) * 64;
  int wc = (wave & 1) * 64;
  int ln15 = lane & 15;
  int kq = lane >> 4;

  float* C = Og + (size_t)bz * (2048 * 1024);
  const float* rs = rowsum + (size_t)bz * 2048;
#pragma unroll
  for (int i = 0; i < 4; ++i) {
    int row0 = m0 + wr + i * 16 + kq * 4;
#pragma unroll
    for (int r = 0; r < 4; ++r) {
      float inv = 1.0f / rs[row0 + r];
#pragma unroll
      for (int j = 0; j < 4; ++j) {
        int col = n0 + wc + j * 16 + ln15;
        atomicAdd(&C[(size_t)(row0 + r) * 1024 + col], acc[i][j][r] * inv);
      }
    }
  }
}

// merged QKV projection: z=0 -> Q, z=1 -> K, z=2 -> V (transposed per batch)
__global__ __launch_bounds__(256, 3) void gemm_qkv(
    const ushort_t* __restrict__ xb, const ushort_t* __restrict__ wq,
    const ushort_t* __restrict__ wk, const ushort_t* __restrict__ wv,
    ushort_t* __restrict__ Qb, ushort_t* __restrict__ Kb,
    ushort_t* __restrict__ Vt) {
  int m0 = blockIdx.x * BM, n0 = blockIdx.y * BN;
  int z = blockIdx.z;
  const ushort_t* B = (z == 0) ? wq : (z == 1) ? wk : wv;

  __shared__ ushort_t As[BM * BK];
  __shared__ ushort_t Bs[BN * BK];

  f32x4 acc[4][4];
#pragma unroll
  for (int i = 0; i < 4; ++i)
#pragma unroll
    for (int j = 0; j < 4; ++j) acc[i][j] = f32x4{0.f, 0.f, 0.f, 0.f};

  gemm_core(xb, B, 1024, 0, 1024, m0, n0, As, Bs, acc);

  int tid = threadIdx.x;
  int lane = tid & 63;
  int wave = tid >> 6;
  int wr = (wave >> 1) * 64;
  int wc = (wave & 1) * 64;
  int ln15 = lane & 15;
  int kq = lane >> 4;

  if (z < 2) {
    ushort_t* C = (z == 0) ? Qb : Kb;
#pragma unroll
    for (int i = 0; i < 4; ++i) {
      int row0 = m0 + wr + i * 16 + kq * 4;
#pragma unroll
      for (int j = 0; j < 4; ++j) {
        int col = n0 + wc + j * 16 + ln15;
#pragma unroll
        for (int r = 0; r < 4; ++r)
          C[(size_t)(row0 + r) * 1024 + col] = f2bf(acc[i][j][r]);
      }
    }
  } else {
    // V transposed: Vt[b][d][n], token gm -> b = gm>>11, n = gm&2047
#pragma unroll
    for (int i = 0; i < 4; ++i) {
      int gm = m0 + wr + i * 16 + kq * 4;
      int b = gm >> 11, nn = gm & 2047;
#pragma unroll
      for (int j = 0; j < 4; ++j) {
        int d = n0 + wc + j * 16 + ln15;
        ushort4v v;
#pragma unroll
        for (int r = 0; r < 4; ++r) v[r] = f2bf(acc[i][j][r]);
        *(ushort4v*)&Vt[(size_t)b * (2048 * 1024) + (size_t)d * 2048 + nn] = v;
      }
    }
  }
}

// ---------------- launch ----------------
extern "C" void kernel_launch(void* const* d_in, const int* in_sizes, int n_in,
                              void* d_out, int out_size, void* d_ws, size_t ws_size,
                              hipStream_t stream) {
  const float* x = (const float*)d_in[0];
  const float* Wq = (const float*)d_in[1];
  const float* Wk = (const float*)d_in[2];
  const float* Wv = (const float*)d_in[3];
  float* out = (float*)d_out;
  char* ws = (char*)d_ws;

  ushort_t* xb = (ushort_t*)(ws);                   // 16 MB
  ushort_t* wqb = (ushort_t*)(ws + (16ull << 20));  // 2 MB
  ushort_t* wkb = (ushort_t*)(ws + (18ull << 20));  // 2 MB
  ushort_t* wvb = (ushort_t*)(ws + (20ull << 20));  // 2 MB
  ushort_t* Qb = (ushort_t*)(ws + (22ull << 20));   // 16 MB
  ushort_t* Kb = (ushort_t*)(ws + (38ull << 20));   // 16 MB
  ushort_t* Vt = (ushort_t*)(ws + (54ull << 20));   // 16 MB (transposed)
  ushort_t* Eb = (ushort_t*)(ws + (70ull << 20));   // 32 MB exp(S) bf16
  float* rowsum = (float*)(ws + (102ull << 20));    // 32 KB fp32

  cast_all_kernel<<<4096 + 3 * 512 + 4 + 4096, 256, 0, stream>>>(
      x, Wq, Wk, Wv, xb, wqb, wkb, wvb, rowsum, out);

  dim3 gQKV(8192 / BM, 1024 / BN, 3);  // (64, 8, 3): x = M dim (XCD pin)
  gemm_qkv<<<gQKV, 256, 0, stream>>>(xb, wqb, wkb, wvb, Qb, Kb, Vt);

  // S-GEMM fused with exp + rowsum atomics
  dim3 gS(2048 / BM, 2048 / BN, 4);  // (16, 16, 4)
  gemm_sexp<<<gS, 256, 0, stream>>>(Qb, Kb, Eb, rowsum, 0.03125f);

  // O-GEMM: split-K balanced chunks, atomicAdd fp32 into zeroed out
  dim3 gO(40, 1024 / BN, 4);  // (40 (m,ks) chunks, 8, 4)
  gemm_osplit<<<gO, 256, 0, stream>>>(Eb, Vt, out, rowsum);
}

// Round 8
// 221.227 us; speedup vs baseline: 1.2106x; 1.2106x over previous
//
#include <hip/hip_runtime.h>
#include <hip/hip_bf16.h>
#include <stdint.h>

typedef unsigned short ushort_t;
typedef __attribute__((ext_vector_type(4))) float f32x4;
typedef __attribute__((ext_vector_type(8))) __bf16 bf16x8;
typedef __attribute__((ext_vector_type(8))) unsigned short ushort8;
typedef __attribute__((ext_vector_type(4))) unsigned short ushort4v;

__device__ __forceinline__ float bf2f(ushort_t u) {
  union { unsigned u32; float f; } x; x.u32 = ((unsigned)u) << 16; return x.f;
}
__device__ __forceinline__ ushort_t f2bf(float f) {
  union { float f; unsigned u; } x; x.f = f;
  unsigned r = x.u + 0x7FFF + ((x.u >> 16) & 1);
  return (ushort_t)(r >> 16);
}

// async global->LDS, 16 bytes per lane (global_load_lds_dwordx4)
__device__ __forceinline__ void gld16(const ushort_t* g, ushort_t* l) {
  __builtin_amdgcn_global_load_lds(
      (const __attribute__((address_space(1))) uint32_t*)g,
      (__attribute__((address_space(3))) uint32_t*)l, 16, 0, 0);
}

// S-GEMM: compacted list of the 136 active causal tiles (n <= m), m-major.
// A skip-predicate 16x16 grid left half the CUs idle while the rest got 4
// active blocks (linear IDs c,c+256,.. share (x,y) and only differ in z).
__constant__ unsigned char SM[136] = {
    0, 1, 1, 2, 2, 2, 3, 3, 3, 3, 4, 4, 4, 4, 4, 5, 5, 5, 5, 5, 5,
    6, 6, 6, 6, 6, 6, 6, 7, 7, 7, 7, 7, 7, 7, 7,
    8, 8, 8, 8, 8, 8, 8, 8, 8, 9, 9, 9, 9, 9, 9, 9, 9, 9, 9,
    10, 10, 10, 10, 10, 10, 10, 10, 10, 10, 10,
    11, 11, 11, 11, 11, 11, 11, 11, 11, 11, 11, 11,
    12, 12, 12, 12, 12, 12, 12, 12, 12, 12, 12, 12, 12,
    13, 13, 13, 13, 13, 13, 13, 13, 13, 13, 13, 13, 13, 13,
    14, 14, 14, 14, 14, 14, 14, 14, 14, 14, 14, 14, 14, 14, 14,
    15, 15, 15, 15, 15, 15, 15, 15, 15, 15, 15, 15, 15, 15, 15, 15};
__constant__ unsigned char SN[136] = {
    0, 0, 1, 0, 1, 2, 0, 1, 2, 3, 0, 1, 2, 3, 4, 0, 1, 2, 3, 4, 5,
    0, 1, 2, 3, 4, 5, 6, 0, 1, 2, 3, 4, 5, 6, 7,
    0, 1, 2, 3, 4, 5, 6, 7, 8, 0, 1, 2, 3, 4, 5, 6, 7, 8, 9,
    0, 1, 2, 3, 4, 5, 6, 7, 8, 9, 10,
    0, 1, 2, 3, 4, 5, 6, 7, 8, 9, 10, 11,
    0, 1, 2, 3, 4, 5, 6, 7, 8, 9, 10, 11, 12,
    0, 1, 2, 3, 4, 5, 6, 7, 8, 9, 10, 11, 12, 13,
    0, 1, 2, 3, 4, 5, 6, 7, 8, 9, 10, 11, 12, 13, 14,
    0, 1, 2, 3, 4, 5, 6, 7, 8, 9, 10, 11, 12, 13, 14, 15};

// ------- merged cast fp32->bf16 (x,Wq,Wk,Wv) + rowsum zero (4 blocks) ------
__global__ __launch_bounds__(256) void cast_all_kernel(
    const float* __restrict__ x, const float* __restrict__ wq,
    const float* __restrict__ wk, const float* __restrict__ wv,
    ushort_t* __restrict__ xb, ushort_t* __restrict__ wqb,
    ushort_t* __restrict__ wkb, ushort_t* __restrict__ wvb,
    float* __restrict__ rowsum) {
  int blk = blockIdx.x;
  if (blk >= 4096 + 1536) {  // rowsum zero: 4 blocks x 2048 floats
    int idx = (blk - (4096 + 1536)) * 256 + threadIdx.x;  // 0..1023
    f32x4 z = {0.f, 0.f, 0.f, 0.f};
    ((f32x4*)rowsum)[idx * 2] = z;
    ((f32x4*)rowsum)[idx * 2 + 1] = z;
    return;
  }
  const float* in;
  ushort_t* out;
  int i;
  if (blk < 4096) {               // x: 8388608 elems = 4096 blocks
    in = x; out = xb; i = blk * 256 + threadIdx.x;
  } else {
    int w = (blk - 4096) >> 9;    // 512 blocks per weight matrix
    int lb = (blk - 4096) & 511;
    in = (w == 0) ? wq : (w == 1) ? wk : wv;
    out = (w == 0) ? wqb : (w == 1) ? wkb : wvb;
    i = lb * 256 + threadIdx.x;
  }
  const f32x4* p = (const f32x4*)in;
  f32x4 a = p[2 * i];
  f32x4 b = p[2 * i + 1];
  ushort8 o;
  o[0] = f2bf(a[0]); o[1] = f2bf(a[1]); o[2] = f2bf(a[2]); o[3] = f2bf(a[3]);
  o[4] = f2bf(b[0]); o[5] = f2bf(b[1]); o[6] = f2bf(b[2]); o[7] = f2bf(b[3]);
  *((ushort8*)out + i) = o;
}

// ---------------- GEMM tile core: C = A * B^T ----------------
// BK=64: 32 MFMA per barrier pair. XOR k-chunk swizzle on the GLOBAL source
// offset (gld16 dest is wave-uniform+lane*16); readers un-swizzle with
// ln15&7 -> 2-way LDS aliasing only (bank conflicts measured 0).
#define BM 128
#define BN 128
#define BK 64

__device__ __forceinline__ void gemm_core(
    const ushort_t* __restrict__ A, const ushort_t* __restrict__ B, int Kd,
    int kStop, int m0, int n0, ushort_t* As, ushort_t* Bs, f32x4 (&acc)[4][4]) {
  int tid = threadIdx.x;
  int lane = tid & 63;
  int wave = tid >> 6;
  int wr = (wave >> 1) * 64;
  int wc = (wave & 1) * 64;
  int ln15 = lane & 15;
  int kq = lane >> 4;

  int row = tid >> 3;                              // 0..31 (base row of chunk)
  int ksw = ((tid & 7) ^ (row & 7)) * 8;           // swizzled k-offset (elems)
  const ushort_t* aB = A + (size_t)(m0 + row) * Kd + ksw;
  const ushort_t* bB = B + (size_t)(n0 + row) * Kd + ksw;
  int xk = ln15 & 7;                               // reader un-swizzle key

  for (int k0 = 0; k0 < kStop; k0 += BK) {
    __syncthreads();
#pragma unroll
    for (int r = 0; r < 4; ++r) {
      gld16(aB + (size_t)(32 * r) * Kd + k0, &As[(tid + 256 * r) * 8]);
      gld16(bB + (size_t)(32 * r) * Kd + k0, &Bs[(tid + 256 * r) * 8]);
    }
    __syncthreads();
#pragma unroll
    for (int s = 0; s < 2; ++s) {
      bf16x8 af[4], bfr[4];
#pragma unroll
      for (int i = 0; i < 4; ++i)
        af[i] = *(const bf16x8*)
            &As[(wr + i * 16 + ln15) * BK + (((s * 4 + kq) ^ xk) * 8)];
#pragma unroll
      for (int j = 0; j < 4; ++j)
        bfr[j] = *(const bf16x8*)
            &Bs[(wc + j * 16 + ln15) * BK + (((s * 4 + kq) ^ xk) * 8)];
#pragma unroll
      for (int i = 0; i < 4; ++i)
#pragma unroll
        for (int j = 0; j < 4; ++j)
          acc[i][j] = __builtin_amdgcn_mfma_f32_16x16x32_bf16(
              af[i], bfr[j], acc[i][j], 0, 0, 0);
    }
  }
}

// S-GEMM fused with softmax numerator. scores*scale have |s|<~2.5 so exp
// without row-max is safe; writes bf16 E=exp(s) (diag-masked) + fp32 rowsum
// atomics. Grid: (136 compacted causal tiles, 4 batches).
// __launch_bounds__ 2nd arg=3: caps unified VGPR+AGPR ~170, no acc spill
// (R3's (256,4)+overflow caused a 1.5GB-scratch disaster).
__global__ __launch_bounds__(256, 3) void gemm_sexp(
    const ushort_t* __restrict__ Qb, const ushort_t* __restrict__ Kb,
    ushort_t* __restrict__ Eb, float* __restrict__ rowsum, float scale) {
  int m0 = SM[blockIdx.x] * BM, n0 = SN[blockIdx.x] * BN;
  int bz = blockIdx.y;
  const ushort_t* A = Qb + (size_t)bz * (2048 * 1024);
  const ushort_t* B = Kb + (size_t)bz * (2048 * 1024);

  __shared__ ushort_t As[BM * BK];
  __shared__ ushort_t Bs[BN * BK];

  f32x4 acc[4][4];
#pragma unroll
  for (int i = 0; i < 4; ++i)
#pragma unroll
    for (int j = 0; j < 4; ++j) acc[i][j] = f32x4{0.f, 0.f, 0.f, 0.f};

  gemm_core(A, B, 1024, 1024, m0, n0, As, Bs, acc);

  int tid = threadIdx.x;
  int lane = tid & 63;
  int wave = tid >> 6;
  int wr = (wave >> 1) * 64;
  int wc = (wave & 1) * 64;
  int ln15 = lane & 15;
  int kq = lane >> 4;

  // C/D layout (verified m89): col = lane&15, row = (lane>>4)*4 + reg
  ushort_t* C = Eb + (size_t)bz * (2048 * 2048);
  float* rs = rowsum + (size_t)bz * 2048;
#pragma unroll
  for (int i = 0; i < 4; ++i) {
    int row0 = m0 + wr + i * 16 + kq * 4;
#pragma unroll
    for (int r = 0; r < 4; ++r) {
      int grow = row0 + r;
      float psum = 0.f;
#pragma unroll
      for (int j = 0; j < 4; ++j) {
        int col = n0 + wc + j * 16 + ln15;
        float e = (col <= grow) ? __expf(acc[i][j][r] * scale) : 0.f;
        C[(size_t)grow * 2048 + col] = f2bf(e);
        psum += e;
      }
      psum += __shfl_xor(psum, 1);
      psum += __shfl_xor(psum, 2);
      psum += __shfl_xor(psum, 4);
      psum += __shfl_xor(psum, 8);
      if (ln15 == 0) atomicAdd(&rs[grow], psum);
    }
  }
}

// O-GEMM: causal K-range (kEnd=(m+1)*128), plain 1/rowsum store epilogue.
// m = (z<2) ? x : 15-x: under round-robin assignment CU c hosts linear IDs
// c and c+256 = same (x,y), z vs z+2 -> complementary m -> every CU gets
// exactly (x+1)*2 + (16-x)*2 = 34 K-iters (was 64 on m=15 CUs; R7's atomic
// split-K alternative cost 76us in epilogue atomics - don't bring it back).
__global__ __launch_bounds__(256, 3) void gemm_out(
    const ushort_t* __restrict__ Eb, const ushort_t* __restrict__ Vt,
    float* __restrict__ Og, const float* __restrict__ rowsum) {
  int m = (blockIdx.z < 2) ? blockIdx.x : 15 - blockIdx.x;
  int m0 = m * BM, n0 = blockIdx.y * BN;
  int bz = blockIdx.z;
  int kStop = m0 + BM;

  const ushort_t* A = Eb + (size_t)bz * (2048 * 2048);
  const ushort_t* B = Vt + (size_t)bz * (1024 * 2048);

  __shared__ ushort_t As[BM * BK];
  __shared__ ushort_t Bs[BN * BK];

  f32x4 acc[4][4];
#pragma unroll
  for (int i = 0; i < 4; ++i)
#pragma unroll
    for (int j = 0; j < 4; ++j) acc[i][j] = f32x4{0.f, 0.f, 0.f, 0.f};

  gemm_core(A, B, 2048, kStop, m0, n0, As, Bs, acc);

  int tid = threadIdx.x;
  int lane = tid & 63;
  int wave = tid >> 6;
  int wr = (wave >> 1) * 64;
  int wc = (wave & 1) * 64;
  int ln15 = lane & 15;
  int kq = lane >> 4;

  float* C = Og + (size_t)bz * (2048 * 1024);
  const float* rs = rowsum + (size_t)bz * 2048;
#pragma unroll
  for (int i = 0; i < 4; ++i) {
    int row0 = m0 + wr + i * 16 + kq * 4;
#pragma unroll
    for (int r = 0; r < 4; ++r) {
      float inv = 1.0f / rs[row0 + r];
#pragma unroll
      for (int j = 0; j < 4; ++j) {
        int col = n0 + wc + j * 16 + ln15;
        C[(size_t)(row0 + r) * 1024 + col] = acc[i][j][r] * inv;
      }
    }
  }
}

// merged QKV projection: z=0 -> Q, z=1 -> K, z=2 -> V (transposed per batch)
__global__ __launch_bounds__(256, 3) void gemm_qkv(
    const ushort_t* __restrict__ xb, const ushort_t* __restrict__ wq,
    const ushort_t* __restrict__ wk, const ushort_t* __restrict__ wv,
    ushort_t* __restrict__ Qb, ushort_t* __restrict__ Kb,
    ushort_t* __restrict__ Vt) {
  int m0 = blockIdx.x * BM, n0 = blockIdx.y * BN;
  int z = blockIdx.z;
  const ushort_t* B = (z == 0) ? wq : (z == 1) ? wk : wv;

  __shared__ ushort_t As[BM * BK];
  __shared__ ushort_t Bs[BN * BK];

  f32x4 acc[4][4];
#pragma unroll
  for (int i = 0; i < 4; ++i)
#pragma unroll
    for (int j = 0; j < 4; ++j) acc[i][j] = f32x4{0.f, 0.f, 0.f, 0.f};

  gemm_core(xb, B, 1024, 1024, m0, n0, As, Bs, acc);

  int tid = threadIdx.x;
  int lane = tid & 63;
  int wave = tid >> 6;
  int wr = (wave >> 1) * 64;
  int wc = (wave & 1) * 64;
  int ln15 = lane & 15;
  int kq = lane >> 4;

  if (z < 2) {
    ushort_t* C = (z == 0) ? Qb : Kb;
#pragma unroll
    for (int i = 0; i < 4; ++i) {
      int row0 = m0 + wr + i * 16 + kq * 4;
#pragma unroll
      for (int j = 0; j < 4; ++j) {
        int col = n0 + wc + j * 16 + ln15;
#pragma unroll
        for (int r = 0; r < 4; ++r)
          C[(size_t)(row0 + r) * 1024 + col] = f2bf(acc[i][j][r]);
      }
    }
  } else {
    // V transposed: Vt[b][d][n], token gm -> b = gm>>11, n = gm&2047
#pragma unroll
    for (int i = 0; i < 4; ++i) {
      int gm = m0 + wr + i * 16 + kq * 4;
      int b = gm >> 11, nn = gm & 2047;
#pragma unroll
      for (int j = 0; j < 4; ++j) {
        int d = n0 + wc + j * 16 + ln15;
        ushort4v v;
#pragma unroll
        for (int r = 0; r < 4; ++r) v[r] = f2bf(acc[i][j][r]);
        *(ushort4v*)&Vt[(size_t)b * (2048 * 1024) + (size_t)d * 2048 + nn] = v;
      }
    }
  }
}

// ---------------- launch ----------------
extern "C" void kernel_launch(void* const* d_in, const int* in_sizes, int n_in,
                              void* d_out, int out_size, void* d_ws, size_t ws_size,
                              hipStream_t stream) {
  const float* x = (const float*)d_in[0];
  const float* Wq = (const float*)d_in[1];
  const float* Wk = (const float*)d_in[2];
  const float* Wv = (const float*)d_in[3];
  float* out = (float*)d_out;
  char* ws = (char*)d_ws;

  ushort_t* xb = (ushort_t*)(ws);                   // 16 MB
  ushort_t* wqb = (ushort_t*)(ws + (16ull << 20));  // 2 MB
  ushort_t* wkb = (ushort_t*)(ws + (18ull << 20));  // 2 MB
  ushort_t* wvb = (ushort_t*)(ws + (20ull << 20));  // 2 MB
  ushort_t* Qb = (ushort_t*)(ws + (22ull << 20));   // 16 MB
  ushort_t* Kb = (ushort_t*)(ws + (38ull << 20));   // 16 MB
  ushort_t* Vt = (ushort_t*)(ws + (54ull << 20));   // 16 MB (transposed)
  ushort_t* Eb = (ushort_t*)(ws + (70ull << 20));   // 32 MB exp(S) bf16
  float* rowsum = (float*)(ws + (102ull << 20));    // 32 KB fp32

  cast_all_kernel<<<4096 + 3 * 512 + 4, 256, 0, stream>>>(
      x, Wq, Wk, Wv, xb, wqb, wkb, wvb, rowsum);

  dim3 gQKV(8192 / BM, 1024 / BN, 3);  // (64, 8, 3): x = M dim (XCD pin)
  gemm_qkv<<<gQKV, 256, 0, stream>>>(xb, wqb, wkb, wvb, Qb, Kb, Vt);

  // S-GEMM fused with exp + rowsum atomics; 136 compacted causal tiles
  dim3 gS(136, 4);
  gemm_sexp<<<gS, 256, 0, stream>>>(Qb, Kb, Eb, rowsum, 0.03125f);

  // O-GEMM: balanced complementary-m pairing, plain stores
  dim3 gO(16, 1024 / BN, 4);
  gemm_out<<<gO, 256, 0, stream>>>(Eb, Vt, out, rowsum);
}